// Round 9
// baseline (1035.609 us; speedup 1.0000x reference)
//
#include <hip/hip_runtime.h>

#define F_IN 165
#define KP_PROJ 168
constexpr float NEG_SLOPE = 0.2f;

// ---- weight transposes + va vectors ----------------------------------------
// t0: projW -> [64][168] padded; t2: W2 -> [64][256]; t1: W1 -> W1t[256][64];
// va[i][k], i = plane*4+head: va_s[h][k] = sum_c W1[k,h*64+c]*att_s[h,c].
__global__ void k_trans(const float* __restrict__ pw, const float* __restrict__ w2,
                        const float* __restrict__ w1, const float* __restrict__ as1w,
                        const float* __restrict__ ad1w,
                        float* __restrict__ t0, float* __restrict__ t2,
                        float* __restrict__ t1, float* __restrict__ va) {
    int i = blockIdx.x * 256 + threadIdx.x;
    const int n0 = 64 * KP_PROJ, n2 = 64 * 256, n1 = 256 * 64;
    if (i < n0) {
        int c = i / KP_PROJ, r = i - c * KP_PROJ;
        t0[i] = (r < F_IN) ? pw[r * 64 + c] : 0.f;
    } else if (i < n0 + n2) {
        int j = i - n0; int c = j >> 8, r = j & 255;
        t2[j] = w2[r * 64 + c];
    } else if (i < n0 + n2 + n1) {
        int j = i - n0 - n2; int c = j >> 6, k = j & 63;  // W1t[c][k] = W1[k][c]
        t1[j] = w1[k * 256 + c];
    } else if (i < n0 + n2 + n1 + 512) {
        int j = i - n0 - n2 - n1;     // 0..511
        int i2 = j >> 6;              // 0..7 = plane*4 + h
        int plane = i2 >> 2, h = i2 & 3, k = j & 63;
        const float* att = plane ? ad1w : as1w;
        float acc = 0.f;
        for (int c = 0; c < 64; ++c)
            acc = fmaf(w1[k * 256 + h * 64 + c], att[h * 64 + c], acc);
        va[j] = acc;
    }
}

// ---- h0 = relu(x @ W + b): Wt[64][168], 32 nodes/block, 4 groups x 8 nodes --
__global__ void k_proj(const float* __restrict__ x, const float* __restrict__ Wt,
                       const float* __restrict__ b, float* __restrict__ h0, int N) {
    __shared__ float xs[32][KP_PROJ];
    int base = blockIdx.x * 32;
    int t = threadIdx.x;
    for (int idx = t; idx < 32 * KP_PROJ; idx += 256) {
        int nl = idx / KP_PROJ, k = idx - nl * KP_PROJ;
        int node = base + nl;
        xs[nl][k] = (node < N && k < F_IN) ? x[(size_t)node * F_IN + k] : 0.f;
    }
    __syncthreads();
    int g = t >> 6, col = t & 63;
    float acc[8];
    float bb = b[col];
#pragma unroll
    for (int m = 0; m < 8; ++m) acc[m] = bb;
    const float* wrow = Wt + col * KP_PROJ;
    for (int k4 = 0; k4 < KP_PROJ / 4; ++k4) {
        float4 wv = *(const float4*)(wrow + k4 * 4);
#pragma unroll
        for (int m = 0; m < 8; ++m) {
            float4 av = *(const float4*)&xs[g * 8 + m][k4 * 4];
            acc[m] = fmaf(av.x, wv.x, acc[m]);
            acc[m] = fmaf(av.y, wv.y, acc[m]);
            acc[m] = fmaf(av.z, wv.z, acc[m]);
            acc[m] = fmaf(av.w, wv.w, acc[m]);
        }
    }
#pragma unroll
    for (int m = 0; m < 8; ++m) {
        int node = base + g * 8 + m;
        if (node < N) h0[(size_t)node * 64 + col] = fmaxf(acc[m], 0.f);
    }
}

// ---- as1/ad1 from h0 via va vectors: wave per node --------------------------
__global__ void k_attv1(const float* __restrict__ h0, const float* __restrict__ va,
                        float* __restrict__ as_, float* __restrict__ ad_, int N) {
    int t = threadIdx.x, lane = t & 63, wv = t >> 6;
    int n = blockIdx.x * 4 + wv;
    if (n >= N) return;
    float hv = h0[(size_t)n * 64 + lane];
    float r0 = hv * va[0 * 64 + lane], r1 = hv * va[1 * 64 + lane];
    float r2 = hv * va[2 * 64 + lane], r3 = hv * va[3 * 64 + lane];
    float r4 = hv * va[4 * 64 + lane], r5 = hv * va[5 * 64 + lane];
    float r6 = hv * va[6 * 64 + lane], r7 = hv * va[7 * 64 + lane];
#pragma unroll
    for (int off = 32; off; off >>= 1) {
        r0 += __shfl_xor(r0, off, 64); r1 += __shfl_xor(r1, off, 64);
        r2 += __shfl_xor(r2, off, 64); r3 += __shfl_xor(r3, off, 64);
        r4 += __shfl_xor(r4, off, 64); r5 += __shfl_xor(r5, off, 64);
        r6 += __shfl_xor(r6, off, 64); r7 += __shfl_xor(r7, off, 64);
    }
    if (lane == 0) {
        *(float4*)(as_ + (size_t)n * 4) = make_float4(r0, r1, r2, r3);
        *(float4*)(ad_ + (size_t)n * 4) = make_float4(r4, r5, r6, r7);
    }
}

// ---- h2lin = h1 @ W2: Wt2[64][256], 32 nodes/block, 4 groups x 8, fused att -
__global__ void k_lin2(const float* __restrict__ h1, const float* __restrict__ Wt,
                       const float* __restrict__ att_s, const float* __restrict__ att_d,
                       float* __restrict__ out, float* __restrict__ as_,
                       float* __restrict__ ad_, int N) {
    __shared__ float hs[32][256];
    int base = blockIdx.x * 32;
    int t = threadIdx.x;
    for (int i = 0; i < 8; ++i) {
        int idx4 = t + i * 256;
        int nl = idx4 >> 6, k4 = idx4 & 63;
        int node = base + nl;
        float4 v = make_float4(0.f, 0.f, 0.f, 0.f);
        if (node < N) v = *(const float4*)(h1 + (size_t)node * 256 + k4 * 4);
        *(float4*)&hs[nl][k4 * 4] = v;
    }
    __syncthreads();
    int g = t >> 6, col = t & 63;
    float acc[8] = {};
    const float* wrow = Wt + col * 256;
    for (int k4 = 0; k4 < 64; ++k4) {
        float4 wv = *(const float4*)(wrow + k4 * 4);
#pragma unroll
        for (int m = 0; m < 8; ++m) {
            float4 av = *(const float4*)&hs[g * 8 + m][k4 * 4];
            acc[m] = fmaf(av.x, wv.x, acc[m]);
            acc[m] = fmaf(av.y, wv.y, acc[m]);
            acc[m] = fmaf(av.z, wv.z, acc[m]);
            acc[m] = fmaf(av.w, wv.w, acc[m]);
        }
    }
    float sw = att_s[col], dw = att_d[col];
#pragma unroll
    for (int m = 0; m < 8; ++m) {
        int node = base + g * 8 + m;
        if (node < N) out[(size_t)node * 64 + col] = acc[m];
        float sv = acc[m] * sw, dv = acc[m] * dw;
#pragma unroll
        for (int off = 32; off; off >>= 1) {
            sv += __shfl_xor(sv, off, 64);
            dv += __shfl_xor(dv, off, 64);
        }
        if (col == 0 && node < N) { as_[node] = sv; ad_[node] = dv; }
    }
}

// ---------------- CSR build: degree, scan, scatter ---------------------------
__global__ void k_deg(const int* __restrict__ ei, int E, int N, int* __restrict__ deg) {
    int total = E + N;
    for (int i = blockIdx.x * blockDim.x + threadIdx.x; i < total; i += gridDim.x * blockDim.x) {
        int dst = (i < E) ? ei[E + i] : (i - E);
        atomicAdd(&deg[dst], 1);
    }
}

__global__ void k_scan_part(const int* __restrict__ deg, int* __restrict__ out,
                            int* __restrict__ partials, int n) {
    __shared__ int tmp[1024];
    int b = blockIdx.x, t = threadIdx.x;
    int i = b * 1024 + t;
    int v = (i < n) ? deg[i] : 0;
    tmp[t] = v;
    __syncthreads();
    for (int off = 1; off < 1024; off <<= 1) {
        int xval = (t >= off) ? tmp[t - off] : 0;
        __syncthreads();
        tmp[t] += xval;
        __syncthreads();
    }
    if (i < n) out[i] = tmp[t] - v; // exclusive
    if (t == 1023) partials[b] = tmp[t];
}

__global__ void k_scan_small(int* __restrict__ partials, int nblk) {
    int lane = threadIdx.x & 63;
    int carry = 0;
    for (int base = 0; base < nblk; base += 64) {
        int idx = base + lane;
        int v = (idx < nblk) ? partials[idx] : 0;
        int orig = v;
#pragma unroll
        for (int off = 1; off < 64; off <<= 1) {
            int u = __shfl_up(v, off, 64);
            if (lane >= off) v += u;
        }
        if (idx < nblk) partials[idx] = carry + v - orig; // exclusive
        carry += __shfl(v, 63, 64);
    }
}

__global__ void k_scan_add(int* __restrict__ rowptr, const int* __restrict__ partials,
                           int n, int total) {
    int i = blockIdx.x * 1024 + threadIdx.x;
    if (i < n) rowptr[i] += partials[blockIdx.x];
    if (i == 0) rowptr[n] = total;
}

__global__ void k_scatter(const int* __restrict__ ei, int E, int N,
                          const int* __restrict__ rowptr, int* __restrict__ cursor,
                          int* __restrict__ csrc, int* __restrict__ cdst) {
    int total = E + N;
    for (int i = blockIdx.x * blockDim.x + threadIdx.x; i < total; i += gridDim.x * blockDim.x) {
        int src, dst;
        if (i < E) { src = ei[i]; dst = ei[E + i]; }
        else { src = i - E; dst = i - E; }
        int pos = rowptr[dst] + atomicAdd(&cursor[dst], 1);
        csrc[pos] = src;
        cdst[pos] = dst;
    }
}

// ------------- per-edge softmax weights (layer 1, 4 heads, AoS float4) -------
__global__ void k_edgew1(const int* __restrict__ csrc, const int* __restrict__ cdst,
                         const float* __restrict__ as_, const float* __restrict__ ad_,
                         float* __restrict__ wexp, int total) {
    for (int i = blockIdx.x * blockDim.x + threadIdx.x; i < total; i += gridDim.x * blockDim.x) {
        int s = csrc[i], d = cdst[i];
        float4 a = *(const float4*)(as_ + (size_t)s * 4);
        float4 b = *(const float4*)(ad_ + (size_t)d * 4);
        float z0 = a.x + b.x, z1 = a.y + b.y, z2 = a.z + b.z, z3 = a.w + b.w;
        z0 = (z0 > 0.f) ? z0 : NEG_SLOPE * z0;
        z1 = (z1 > 0.f) ? z1 : NEG_SLOPE * z1;
        z2 = (z2 > 0.f) ? z2 : NEG_SLOPE * z2;
        z3 = (z3 > 0.f) ? z3 : NEG_SLOPE * z3;
        *(float4*)(wexp + (size_t)i * 4) =
            make_float4(__expf(z0), __expf(z1), __expf(z2), __expf(z3));
    }
}

// ------------- per-edge softmax weights (layer 2, 1 head) --------------------
__global__ void k_edgew2(const int* __restrict__ csrc, const int* __restrict__ cdst,
                         const float* __restrict__ as_, const float* __restrict__ ad_,
                         float* __restrict__ wexp, int total) {
    for (int i = blockIdx.x * blockDim.x + threadIdx.x; i < total; i += gridDim.x * blockDim.x) {
        float z = as_[csrc[i]] + ad_[cdst[i]];
        z = (z > 0.f) ? z : NEG_SLOPE * z;
        wexp[i] = __expf(z);
    }
}

// --------- GAT layer 1 fused: h0-domain aggregation + per-block W1t GEMM -----
// Phase 1: wave per dst, 4 edge-slots x 16 lanes, float4 gathers.
// Phase 2: transposed W1t[col][64] -> 16 float4 global loads + float4 LDS
// broadcasts per thread (2x fewer instructions than scalar version).
__global__ void k_gat1f(const float* __restrict__ h0, const float* __restrict__ wexp4,
                        const int* __restrict__ rowptr, const int* __restrict__ csrc,
                        const float* __restrict__ W1t, const float* __restrict__ b1,
                        float* __restrict__ h1out, int N) {
    __shared__ float agg[4][256];
    int t = threadIdx.x, wv = t >> 6, lane = t & 63;
    int slot = lane >> 4, sl = lane & 15;
    int d = blockIdx.x * 4 + wv;
    if (d < N) {
        int s0 = rowptr[d], e0 = rowptr[d + 1];
        float a00=0,a01=0,a02=0,a03=0;
        float a10=0,a11=0,a12=0,a13=0;
        float a20=0,a21=0,a22=0,a23=0;
        float a30=0,a31=0,a32=0,a33=0;
        float d0=0,d1=0,d2=0,d3=0;
        const float* hb = h0 + sl * 4;
        for (int j = s0 + slot; j < e0; j += 4) {
            int s = csrc[j];
            float4 w = *(const float4*)(wexp4 + (size_t)j * 4);
            float4 hv = *(const float4*)(hb + (size_t)s * 64);
            a00 = fmaf(w.x, hv.x, a00); a01 = fmaf(w.x, hv.y, a01);
            a02 = fmaf(w.x, hv.z, a02); a03 = fmaf(w.x, hv.w, a03);
            a10 = fmaf(w.y, hv.x, a10); a11 = fmaf(w.y, hv.y, a11);
            a12 = fmaf(w.y, hv.z, a12); a13 = fmaf(w.y, hv.w, a13);
            a20 = fmaf(w.z, hv.x, a20); a21 = fmaf(w.z, hv.y, a21);
            a22 = fmaf(w.z, hv.z, a22); a23 = fmaf(w.z, hv.w, a23);
            a30 = fmaf(w.w, hv.x, a30); a31 = fmaf(w.w, hv.y, a31);
            a32 = fmaf(w.w, hv.z, a32); a33 = fmaf(w.w, hv.w, a33);
            d0 += w.x; d1 += w.y; d2 += w.z; d3 += w.w;
        }
#pragma unroll
        for (int off = 16; off <= 32; off <<= 1) {
            a00 += __shfl_xor(a00, off, 64); a01 += __shfl_xor(a01, off, 64);
            a02 += __shfl_xor(a02, off, 64); a03 += __shfl_xor(a03, off, 64);
            a10 += __shfl_xor(a10, off, 64); a11 += __shfl_xor(a11, off, 64);
            a12 += __shfl_xor(a12, off, 64); a13 += __shfl_xor(a13, off, 64);
            a20 += __shfl_xor(a20, off, 64); a21 += __shfl_xor(a21, off, 64);
            a22 += __shfl_xor(a22, off, 64); a23 += __shfl_xor(a23, off, 64);
            a30 += __shfl_xor(a30, off, 64); a31 += __shfl_xor(a31, off, 64);
            a32 += __shfl_xor(a32, off, 64); a33 += __shfl_xor(a33, off, 64);
            d0  += __shfl_xor(d0,  off, 64); d1  += __shfl_xor(d1,  off, 64);
            d2  += __shfl_xor(d2,  off, 64); d3  += __shfl_xor(d3,  off, 64);
        }
        if (slot == 0) {
            float i0 = 1.f / d0, i1 = 1.f / d1, i2 = 1.f / d2, i3 = 1.f / d3;
            *(float4*)&agg[wv][  0 + sl * 4] = make_float4(a00*i0, a01*i0, a02*i0, a03*i0);
            *(float4*)&agg[wv][ 64 + sl * 4] = make_float4(a10*i1, a11*i1, a12*i1, a13*i1);
            *(float4*)&agg[wv][128 + sl * 4] = make_float4(a20*i2, a21*i2, a22*i2, a23*i2);
            *(float4*)&agg[wv][192 + sl * 4] = make_float4(a30*i3, a31*i3, a32*i3, a33*i3);
        }
    }
    __syncthreads();
    int h4 = (t >> 6) * 64;  // head base, wave-uniform
    float o0 = 0.f, o1 = 0.f, o2 = 0.f, o3 = 0.f;
    const float* wrow = W1t + t * 64;
    for (int k4 = 0; k4 < 16; ++k4) {
        float4 w = *(const float4*)(wrow + k4 * 4);
        float4 g0 = *(const float4*)&agg[0][h4 + k4 * 4];
        float4 g1 = *(const float4*)&agg[1][h4 + k4 * 4];
        float4 g2 = *(const float4*)&agg[2][h4 + k4 * 4];
        float4 g3 = *(const float4*)&agg[3][h4 + k4 * 4];
        o0 = fmaf(g0.x, w.x, o0); o0 = fmaf(g0.y, w.y, o0);
        o0 = fmaf(g0.z, w.z, o0); o0 = fmaf(g0.w, w.w, o0);
        o1 = fmaf(g1.x, w.x, o1); o1 = fmaf(g1.y, w.y, o1);
        o1 = fmaf(g1.z, w.z, o1); o1 = fmaf(g1.w, w.w, o1);
        o2 = fmaf(g2.x, w.x, o2); o2 = fmaf(g2.y, w.y, o2);
        o2 = fmaf(g2.z, w.z, o2); o2 = fmaf(g2.w, w.w, o2);
        o3 = fmaf(g3.x, w.x, o3); o3 = fmaf(g3.y, w.y, o3);
        o3 = fmaf(g3.z, w.z, o3); o3 = fmaf(g3.w, w.w, o3);
    }
    float bb = b1[t];
    int base = blockIdx.x * 4;
    if (base + 0 < N) h1out[(size_t)(base + 0) * 256 + t] = fmaxf(o0 + bb, 0.f);
    if (base + 1 < N) h1out[(size_t)(base + 1) * 256 + t] = fmaxf(o1 + bb, 0.f);
    if (base + 2 < N) h1out[(size_t)(base + 2) * 256 + t] = fmaxf(o2 + bb, 0.f);
    if (base + 3 < N) h1out[(size_t)(base + 3) * 256 + t] = fmaxf(o3 + bb, 0.f);
}

// --------- GAT layer 2 (1 head): wave per dst, 4 slots x 16 lanes, float4 ----
__global__ void k_gat2(const float* __restrict__ hlin, const float* __restrict__ wexp,
                       const int* __restrict__ rowptr, const int* __restrict__ csrc,
                       const float* __restrict__ bias, const float* __restrict__ clsW,
                       const float* __restrict__ clsB, float* __restrict__ out, int N) {
    int t = threadIdx.x, wv = t >> 6, lane = t & 63;
    int slot = lane >> 4, sl = lane & 15;
    int d = blockIdx.x * 4 + wv;
    if (d >= N) return;
    int s0 = rowptr[d], e0 = rowptr[d + 1];
    float ax = 0.f, ay = 0.f, az = 0.f, aw = 0.f, den = 0.f;
    const float* hb = hlin + sl * 4;
    for (int j = s0 + slot; j < e0; j += 4) {
        int s = csrc[j];
        float w = wexp[j];
        float4 hv = *(const float4*)(hb + (size_t)s * 64);
        ax = fmaf(w, hv.x, ax); ay = fmaf(w, hv.y, ay);
        az = fmaf(w, hv.z, az); aw = fmaf(w, hv.w, aw);
        den += w;
    }
#pragma unroll
    for (int off = 16; off <= 32; off <<= 1) {
        ax += __shfl_xor(ax, off, 64); ay += __shfl_xor(ay, off, 64);
        az += __shfl_xor(az, off, 64); aw += __shfl_xor(aw, off, 64);
        den += __shfl_xor(den, off, 64);
    }
    float inv = 1.f / den;
    float4 bb = *(const float4*)(bias + sl * 4);
    float4 cw = *(const float4*)(clsW + sl * 4);
    float p = fmaxf(fmaf(ax, inv, bb.x), 0.f) * cw.x
            + fmaxf(fmaf(ay, inv, bb.y), 0.f) * cw.y
            + fmaxf(fmaf(az, inv, bb.z), 0.f) * cw.z
            + fmaxf(fmaf(aw, inv, bb.w), 0.f) * cw.w;
#pragma unroll
    for (int off = 1; off <= 8; off <<= 1) p += __shfl_xor(p, off, 64);
    if (lane == 0) out[d] = p + clsB[0];
}

extern "C" void kernel_launch(void* const* d_in, const int* in_sizes, int n_in,
                              void* d_out, int out_size, void* d_ws, size_t ws_size,
                              hipStream_t stream) {
    const float* x     = (const float*)d_in[0];
    const int*   ei    = (const int*)d_in[1];
    const float* projW = (const float*)d_in[2];
    const float* projB = (const float*)d_in[3];
    const float* W1    = (const float*)d_in[4];
    const float* as1w  = (const float*)d_in[5];
    const float* ad1w  = (const float*)d_in[6];
    const float* b1    = (const float*)d_in[7];
    const float* W2    = (const float*)d_in[8];
    const float* as2w  = (const float*)d_in[9];
    const float* ad2w  = (const float*)d_in[10];
    const float* b2    = (const float*)d_in[11];
    const float* clsW  = (const float*)d_in[12];
    const float* clsB  = (const float*)d_in[13];
    float* out = (float*)d_out;

    const int N = in_sizes[0] / F_IN;
    const int E = in_sizes[1] / 2;
    const int total = E + N;

    char* ws = (char*)d_ws;
    size_t off = 0;
    auto alloc = [&](size_t bytes) -> void* {
        void* p = ws + off;
        off += (bytes + 255) & ~(size_t)255;
        return p;
    };
    float* h0     = (float*)alloc((size_t)N * 64 * 4);   // reused as h2lin
    float* h1     = (float*)alloc((size_t)N * 256 * 4);
    float* as1    = (float*)alloc((size_t)N * 4 * 4);
    float* ad1    = (float*)alloc((size_t)N * 4 * 4);
    float* as2    = (float*)alloc((size_t)N * 4);
    float* ad2    = (float*)alloc((size_t)N * 4);
    int*   deg    = (int*)alloc((size_t)N * 4);
    int*   rowptr = (int*)alloc((size_t)(N + 1) * 4);
    int*   cursor = (int*)alloc((size_t)N * 4);
    int*   parts  = (int*)alloc(1024 * 4);
    int*   csrc   = (int*)alloc((size_t)total * 4);
    int*   cdst   = (int*)alloc((size_t)total * 4);
    float* wexp1  = (float*)alloc((size_t)total * 4 * 4);
    float* wexp2  = (float*)alloc((size_t)total * 4);
    float* wt0    = (float*)alloc(64 * KP_PROJ * 4);
    float* wt2    = (float*)alloc(64 * 256 * 4);
    float* w1t    = (float*)alloc(256 * 64 * 4);
    float* va     = (float*)alloc(512 * 4);
    float* h2lin  = h0;

    // weight transposes + va vectors
    const int ntr = 64 * KP_PROJ + 64 * 256 + 256 * 64 + 512;
    k_trans<<<(ntr + 255) / 256, 256, 0, stream>>>(
        projW, W2, W1, as1w, ad1w, wt0, wt2, w1t, va);

    // CSR build
    hipMemsetAsync(deg, 0, (size_t)N * 4, stream);
    hipMemsetAsync(cursor, 0, (size_t)N * 4, stream);
    k_deg<<<1024, 256, 0, stream>>>(ei, E, N, deg);
    int nblk = (N + 1023) / 1024;
    k_scan_part<<<nblk, 1024, 0, stream>>>(deg, rowptr, parts, N);
    k_scan_small<<<1, 64, 0, stream>>>(parts, nblk);
    k_scan_add<<<nblk, 1024, 0, stream>>>(rowptr, parts, N, total);
    k_scatter<<<1024, 256, 0, stream>>>(ei, E, N, rowptr, cursor, csrc, cdst);

    // MLP in
    k_proj<<<(N + 31) / 32, 256, 0, stream>>>(x, wt0, projB, h0, N);

    // GAT layer 1 (h0-domain aggregation)
    k_attv1<<<(N + 3) / 4, 256, 0, stream>>>(h0, va, as1, ad1, N);
    k_edgew1<<<2048, 256, 0, stream>>>(csrc, cdst, as1, ad1, wexp1, total);
    k_gat1f<<<(N + 3) / 4, 256, 0, stream>>>(h0, wexp1, rowptr, csrc, w1t, b1, h1, N);

    // GAT layer 2 + classifier
    k_lin2<<<(N + 31) / 32, 256, 0, stream>>>(h1, wt2, as2w, ad2w, h2lin, as2, ad2, N);
    k_edgew2<<<2048, 256, 0, stream>>>(csrc, cdst, as2, ad2, wexp2, total);
    k_gat2<<<(N + 3) / 4, 256, 0, stream>>>(h2lin, wexp2, rowptr, csrc, b2,
                                            clsW, clsB, out, N);
}

// Round 10
// 337.616 us; speedup vs baseline: 3.0674x; 3.0674x over previous
//
#include <hip/hip_runtime.h>

#define F_IN 165
#define KP_PROJ 168
constexpr float NEG_SLOPE = 0.2f;

// ---- weight transposes + va vectors (va[i][k], i = plane*4+head) -----------
__global__ void k_trans(const float* __restrict__ pw, const float* __restrict__ w2,
                        const float* __restrict__ w1, const float* __restrict__ as1w,
                        const float* __restrict__ ad1w,
                        float* __restrict__ t0, float* __restrict__ t2,
                        float* __restrict__ va) {
    int i = blockIdx.x * 256 + threadIdx.x;
    const int n0 = 64 * KP_PROJ, n2 = 64 * 256;
    if (i < n0) {
        int c = i / KP_PROJ, r = i - c * KP_PROJ;
        t0[i] = (r < F_IN) ? pw[r * 64 + c] : 0.f;
    } else if (i < n0 + n2) {
        int j = i - n0; int c = j >> 8, r = j & 255;
        t2[j] = w2[r * 64 + c];
    } else if (i < n0 + n2 + 512) {
        int j = i - n0 - n2;          // 0..511
        int i2 = j >> 6;              // 0..7 = plane*4 + h
        int plane = i2 >> 2, h = i2 & 3, k = j & 63;
        const float* att = plane ? ad1w : as1w;
        float acc = 0.f;
        for (int c = 0; c < 64; ++c)
            acc = fmaf(w1[k * 256 + h * 64 + c], att[h * 64 + c], acc);
        va[j] = acc;
    }
}

// ---- h0 = relu(x @ W + b): Wt[64][168], 32 nodes/block, 4 groups x 8 nodes --
__global__ void k_proj(const float* __restrict__ x, const float* __restrict__ Wt,
                       const float* __restrict__ b, float* __restrict__ h0, int N) {
    __shared__ float xs[32][KP_PROJ];
    int base = blockIdx.x * 32;
    int t = threadIdx.x;
    for (int idx = t; idx < 32 * KP_PROJ; idx += 256) {
        int nl = idx / KP_PROJ, k = idx - nl * KP_PROJ;
        int node = base + nl;
        xs[nl][k] = (node < N && k < F_IN) ? x[(size_t)node * F_IN + k] : 0.f;
    }
    __syncthreads();
    int g = t >> 6, col = t & 63;
    float acc[8];
    float bb = b[col];
#pragma unroll
    for (int m = 0; m < 8; ++m) acc[m] = bb;
    const float* wrow = Wt + col * KP_PROJ;
    for (int k4 = 0; k4 < KP_PROJ / 4; ++k4) {
        float4 wv = *(const float4*)(wrow + k4 * 4);
#pragma unroll
        for (int m = 0; m < 8; ++m) {
            float4 av = *(const float4*)&xs[g * 8 + m][k4 * 4];
            acc[m] = fmaf(av.x, wv.x, acc[m]);
            acc[m] = fmaf(av.y, wv.y, acc[m]);
            acc[m] = fmaf(av.z, wv.z, acc[m]);
            acc[m] = fmaf(av.w, wv.w, acc[m]);
        }
    }
#pragma unroll
    for (int m = 0; m < 8; ++m) {
        int node = base + g * 8 + m;
        if (node < N) h0[(size_t)node * 64 + col] = fmaxf(acc[m], 0.f);
    }
}

// ---- as1/ad1 from h0 via va vectors: wave per node --------------------------
__global__ void k_attv1(const float* __restrict__ h0, const float* __restrict__ va,
                        float* __restrict__ as_, float* __restrict__ ad_, int N) {
    int t = threadIdx.x, lane = t & 63, wv = t >> 6;
    int n = blockIdx.x * 4 + wv;
    if (n >= N) return;
    float hv = h0[(size_t)n * 64 + lane];
    float r0 = hv * va[0 * 64 + lane], r1 = hv * va[1 * 64 + lane];
    float r2 = hv * va[2 * 64 + lane], r3 = hv * va[3 * 64 + lane];
    float r4 = hv * va[4 * 64 + lane], r5 = hv * va[5 * 64 + lane];
    float r6 = hv * va[6 * 64 + lane], r7 = hv * va[7 * 64 + lane];
#pragma unroll
    for (int off = 32; off; off >>= 1) {
        r0 += __shfl_xor(r0, off, 64); r1 += __shfl_xor(r1, off, 64);
        r2 += __shfl_xor(r2, off, 64); r3 += __shfl_xor(r3, off, 64);
        r4 += __shfl_xor(r4, off, 64); r5 += __shfl_xor(r5, off, 64);
        r6 += __shfl_xor(r6, off, 64); r7 += __shfl_xor(r7, off, 64);
    }
    if (lane == 0) {
        *(float4*)(as_ + (size_t)n * 4) = make_float4(r0, r1, r2, r3);
        *(float4*)(ad_ + (size_t)n * 4) = make_float4(r4, r5, r6, r7);
    }
}

// ---- h2lin = h1 @ W2: Wt2[64][256], 32 nodes/block, 4 groups x 8, fused att -
__global__ void k_lin2(const float* __restrict__ h1, const float* __restrict__ Wt,
                       const float* __restrict__ att_s, const float* __restrict__ att_d,
                       float* __restrict__ out, float* __restrict__ as_,
                       float* __restrict__ ad_, int N) {
    __shared__ float hs[32][256];
    int base = blockIdx.x * 32;
    int t = threadIdx.x;
    for (int i = 0; i < 8; ++i) {
        int idx4 = t + i * 256;
        int nl = idx4 >> 6, k4 = idx4 & 63;
        int node = base + nl;
        float4 v = make_float4(0.f, 0.f, 0.f, 0.f);
        if (node < N) v = *(const float4*)(h1 + (size_t)node * 256 + k4 * 4);
        *(float4*)&hs[nl][k4 * 4] = v;
    }
    __syncthreads();
    int g = t >> 6, col = t & 63;
    float acc[8] = {};
    const float* wrow = Wt + col * 256;
    for (int k4 = 0; k4 < 64; ++k4) {
        float4 wv = *(const float4*)(wrow + k4 * 4);
#pragma unroll
        for (int m = 0; m < 8; ++m) {
            float4 av = *(const float4*)&hs[g * 8 + m][k4 * 4];
            acc[m] = fmaf(av.x, wv.x, acc[m]);
            acc[m] = fmaf(av.y, wv.y, acc[m]);
            acc[m] = fmaf(av.z, wv.z, acc[m]);
            acc[m] = fmaf(av.w, wv.w, acc[m]);
        }
    }
    float sw = att_s[col], dw = att_d[col];
#pragma unroll
    for (int m = 0; m < 8; ++m) {
        int node = base + g * 8 + m;
        if (node < N) out[(size_t)node * 64 + col] = acc[m];
        float sv = acc[m] * sw, dv = acc[m] * dw;
#pragma unroll
        for (int off = 32; off; off >>= 1) {
            sv += __shfl_xor(sv, off, 64);
            dv += __shfl_xor(dv, off, 64);
        }
        if (col == 0 && node < N) { as_[node] = sv; ad_[node] = dv; }
    }
}

// ---------------- CSR build: degree, scan, scatter ---------------------------
__global__ void k_deg(const int* __restrict__ ei, int E, int N, int* __restrict__ deg) {
    int total = E + N;
    for (int i = blockIdx.x * blockDim.x + threadIdx.x; i < total; i += gridDim.x * blockDim.x) {
        int dst = (i < E) ? ei[E + i] : (i - E);
        atomicAdd(&deg[dst], 1);
    }
}

__global__ void k_scan_part(const int* __restrict__ deg, int* __restrict__ out,
                            int* __restrict__ partials, int n) {
    __shared__ int tmp[1024];
    int b = blockIdx.x, t = threadIdx.x;
    int i = b * 1024 + t;
    int v = (i < n) ? deg[i] : 0;
    tmp[t] = v;
    __syncthreads();
    for (int off = 1; off < 1024; off <<= 1) {
        int xval = (t >= off) ? tmp[t - off] : 0;
        __syncthreads();
        tmp[t] += xval;
        __syncthreads();
    }
    if (i < n) out[i] = tmp[t] - v; // exclusive
    if (t == 1023) partials[b] = tmp[t];
}

__global__ void k_scan_small(int* __restrict__ partials, int nblk) {
    int lane = threadIdx.x & 63;
    int carry = 0;
    for (int base = 0; base < nblk; base += 64) {
        int idx = base + lane;
        int v = (idx < nblk) ? partials[idx] : 0;
        int orig = v;
#pragma unroll
        for (int off = 1; off < 64; off <<= 1) {
            int u = __shfl_up(v, off, 64);
            if (lane >= off) v += u;
        }
        if (idx < nblk) partials[idx] = carry + v - orig; // exclusive
        carry += __shfl(v, 63, 64);
    }
}

__global__ void k_scan_add(int* __restrict__ rowptr, const int* __restrict__ partials,
                           int n, int total) {
    int i = blockIdx.x * 1024 + threadIdx.x;
    if (i < n) rowptr[i] += partials[blockIdx.x];
    if (i == 0) rowptr[n] = total;
}

__global__ void k_scatter(const int* __restrict__ ei, int E, int N,
                          const int* __restrict__ rowptr, int* __restrict__ cursor,
                          int* __restrict__ csrc, int* __restrict__ cdst) {
    int total = E + N;
    for (int i = blockIdx.x * blockDim.x + threadIdx.x; i < total; i += gridDim.x * blockDim.x) {
        int src, dst;
        if (i < E) { src = ei[i]; dst = ei[E + i]; }
        else { src = i - E; dst = i - E; }
        int pos = rowptr[dst] + atomicAdd(&cursor[dst], 1);
        csrc[pos] = src;
        cdst[pos] = dst;
    }
}

// ------------- per-edge softmax weights (layer 1, 4 heads, AoS float4) -------
__global__ void k_edgew1(const int* __restrict__ csrc, const int* __restrict__ cdst,
                         const float* __restrict__ as_, const float* __restrict__ ad_,
                         float* __restrict__ wexp, int total) {
    for (int i = blockIdx.x * blockDim.x + threadIdx.x; i < total; i += gridDim.x * blockDim.x) {
        int s = csrc[i], d = cdst[i];
        float4 a = *(const float4*)(as_ + (size_t)s * 4);
        float4 b = *(const float4*)(ad_ + (size_t)d * 4);
        float z0 = a.x + b.x, z1 = a.y + b.y, z2 = a.z + b.z, z3 = a.w + b.w;
        z0 = (z0 > 0.f) ? z0 : NEG_SLOPE * z0;
        z1 = (z1 > 0.f) ? z1 : NEG_SLOPE * z1;
        z2 = (z2 > 0.f) ? z2 : NEG_SLOPE * z2;
        z3 = (z3 > 0.f) ? z3 : NEG_SLOPE * z3;
        *(float4*)(wexp + (size_t)i * 4) =
            make_float4(__expf(z0), __expf(z1), __expf(z2), __expf(z3));
    }
}

// --------- GAT layer 1 fused: h0-domain aggregation + per-block W1 GEMM ------
// Phase 1: wave per dst, 4 edge-slots x 16 lanes, float4 gathers.
// Phase 2: SCALAR W1 reads (coalesced, L2-resident). Do NOT vectorize phase 2:
// the fully-unrollable float4 variant spills ~3.5 GB of scratch (rounds 4/5/9).
__global__ void k_gat1f(const float* __restrict__ h0, const float* __restrict__ wexp4,
                        const int* __restrict__ rowptr, const int* __restrict__ csrc,
                        const float* __restrict__ W1, const float* __restrict__ b1,
                        float* __restrict__ h1out, int N) {
    __shared__ float agg[4][256];
    int t = threadIdx.x, wv = t >> 6, lane = t & 63;
    int slot = lane >> 4, sl = lane & 15;
    int d = blockIdx.x * 4 + wv;
    if (d < N) {
        int s0 = rowptr[d], e0 = rowptr[d + 1];
        float a00=0,a01=0,a02=0,a03=0;
        float a10=0,a11=0,a12=0,a13=0;
        float a20=0,a21=0,a22=0,a23=0;
        float a30=0,a31=0,a32=0,a33=0;
        float d0=0,d1=0,d2=0,d3=0;
        const float* hb = h0 + sl * 4;
        for (int j = s0 + slot; j < e0; j += 4) {
            int s = csrc[j];
            float4 w = *(const float4*)(wexp4 + (size_t)j * 4);
            float4 hv = *(const float4*)(hb + (size_t)s * 64);
            a00 = fmaf(w.x, hv.x, a00); a01 = fmaf(w.x, hv.y, a01);
            a02 = fmaf(w.x, hv.z, a02); a03 = fmaf(w.x, hv.w, a03);
            a10 = fmaf(w.y, hv.x, a10); a11 = fmaf(w.y, hv.y, a11);
            a12 = fmaf(w.y, hv.z, a12); a13 = fmaf(w.y, hv.w, a13);
            a20 = fmaf(w.z, hv.x, a20); a21 = fmaf(w.z, hv.y, a21);
            a22 = fmaf(w.z, hv.z, a22); a23 = fmaf(w.z, hv.w, a23);
            a30 = fmaf(w.w, hv.x, a30); a31 = fmaf(w.w, hv.y, a31);
            a32 = fmaf(w.w, hv.z, a32); a33 = fmaf(w.w, hv.w, a33);
            d0 += w.x; d1 += w.y; d2 += w.z; d3 += w.w;
        }
#pragma unroll
        for (int off = 16; off <= 32; off <<= 1) {
            a00 += __shfl_xor(a00, off, 64); a01 += __shfl_xor(a01, off, 64);
            a02 += __shfl_xor(a02, off, 64); a03 += __shfl_xor(a03, off, 64);
            a10 += __shfl_xor(a10, off, 64); a11 += __shfl_xor(a11, off, 64);
            a12 += __shfl_xor(a12, off, 64); a13 += __shfl_xor(a13, off, 64);
            a20 += __shfl_xor(a20, off, 64); a21 += __shfl_xor(a21, off, 64);
            a22 += __shfl_xor(a22, off, 64); a23 += __shfl_xor(a23, off, 64);
            a30 += __shfl_xor(a30, off, 64); a31 += __shfl_xor(a31, off, 64);
            a32 += __shfl_xor(a32, off, 64); a33 += __shfl_xor(a33, off, 64);
            d0  += __shfl_xor(d0,  off, 64); d1  += __shfl_xor(d1,  off, 64);
            d2  += __shfl_xor(d2,  off, 64); d3  += __shfl_xor(d3,  off, 64);
        }
        if (slot == 0) {
            float i0 = 1.f / d0, i1 = 1.f / d1, i2 = 1.f / d2, i3 = 1.f / d3;
            *(float4*)&agg[wv][  0 + sl * 4] = make_float4(a00*i0, a01*i0, a02*i0, a03*i0);
            *(float4*)&agg[wv][ 64 + sl * 4] = make_float4(a10*i1, a11*i1, a12*i1, a13*i1);
            *(float4*)&agg[wv][128 + sl * 4] = make_float4(a20*i2, a21*i2, a22*i2, a23*i2);
            *(float4*)&agg[wv][192 + sl * 4] = make_float4(a30*i3, a31*i3, a32*i3, a33*i3);
        }
    }
    __syncthreads();
    int h = t >> 6;
    float o0 = 0.f, o1 = 0.f, o2 = 0.f, o3 = 0.f;
    for (int k = 0; k < 64; ++k) {
        float wv1 = W1[k * 256 + t];
        o0 = fmaf(agg[0][h * 64 + k], wv1, o0);
        o1 = fmaf(agg[1][h * 64 + k], wv1, o1);
        o2 = fmaf(agg[2][h * 64 + k], wv1, o2);
        o3 = fmaf(agg[3][h * 64 + k], wv1, o3);
    }
    float bb = b1[t];
    int base = blockIdx.x * 4;
    if (base + 0 < N) h1out[(size_t)(base + 0) * 256 + t] = fmaxf(o0 + bb, 0.f);
    if (base + 1 < N) h1out[(size_t)(base + 1) * 256 + t] = fmaxf(o1 + bb, 0.f);
    if (base + 2 < N) h1out[(size_t)(base + 2) * 256 + t] = fmaxf(o2 + bb, 0.f);
    if (base + 3 < N) h1out[(size_t)(base + 3) * 256 + t] = fmaxf(o3 + bb, 0.f);
}

// --------- GAT layer 2 (1 head): wave per dst, fused edge-weight + classifier
// Edge weight computed inline: as2[s] is an L2-resident 4B gather, ad2[d] is
// wave-uniform. Deletes the separate k_edgew2 pass entirely.
__global__ void k_gat2(const float* __restrict__ hlin, const float* __restrict__ as2,
                       const float* __restrict__ ad2, const int* __restrict__ rowptr,
                       const int* __restrict__ csrc, const float* __restrict__ bias,
                       const float* __restrict__ clsW, const float* __restrict__ clsB,
                       float* __restrict__ out, int N) {
    int t = threadIdx.x, wv = t >> 6, lane = t & 63;
    int slot = lane >> 4, sl = lane & 15;
    int d = blockIdx.x * 4 + wv;
    if (d >= N) return;
    int s0 = rowptr[d], e0 = rowptr[d + 1];
    float add = ad2[d];
    float ax = 0.f, ay = 0.f, az = 0.f, aw = 0.f, den = 0.f;
    const float* hb = hlin + sl * 4;
    for (int j = s0 + slot; j < e0; j += 4) {
        int s = csrc[j];
        float z = as2[s] + add;
        z = (z > 0.f) ? z : NEG_SLOPE * z;
        float w = __expf(z);
        float4 hv = *(const float4*)(hb + (size_t)s * 64);
        ax = fmaf(w, hv.x, ax); ay = fmaf(w, hv.y, ay);
        az = fmaf(w, hv.z, az); aw = fmaf(w, hv.w, aw);
        den += w;
    }
#pragma unroll
    for (int off = 16; off <= 32; off <<= 1) {
        ax += __shfl_xor(ax, off, 64); ay += __shfl_xor(ay, off, 64);
        az += __shfl_xor(az, off, 64); aw += __shfl_xor(aw, off, 64);
        den += __shfl_xor(den, off, 64);
    }
    float inv = 1.f / den;
    float4 bb = *(const float4*)(bias + sl * 4);
    float4 cw = *(const float4*)(clsW + sl * 4);
    float p = fmaxf(fmaf(ax, inv, bb.x), 0.f) * cw.x
            + fmaxf(fmaf(ay, inv, bb.y), 0.f) * cw.y
            + fmaxf(fmaf(az, inv, bb.z), 0.f) * cw.z
            + fmaxf(fmaf(aw, inv, bb.w), 0.f) * cw.w;
#pragma unroll
    for (int off = 1; off <= 8; off <<= 1) p += __shfl_xor(p, off, 64);
    if (lane == 0) out[d] = p + clsB[0];
}

extern "C" void kernel_launch(void* const* d_in, const int* in_sizes, int n_in,
                              void* d_out, int out_size, void* d_ws, size_t ws_size,
                              hipStream_t stream) {
    const float* x     = (const float*)d_in[0];
    const int*   ei    = (const int*)d_in[1];
    const float* projW = (const float*)d_in[2];
    const float* projB = (const float*)d_in[3];
    const float* W1    = (const float*)d_in[4];
    const float* as1w  = (const float*)d_in[5];
    const float* ad1w  = (const float*)d_in[6];
    const float* b1    = (const float*)d_in[7];
    const float* W2    = (const float*)d_in[8];
    const float* as2w  = (const float*)d_in[9];
    const float* ad2w  = (const float*)d_in[10];
    const float* b2    = (const float*)d_in[11];
    const float* clsW  = (const float*)d_in[12];
    const float* clsB  = (const float*)d_in[13];
    float* out = (float*)d_out;

    const int N = in_sizes[0] / F_IN;
    const int E = in_sizes[1] / 2;
    const int total = E + N;

    char* ws = (char*)d_ws;
    size_t off = 0;
    auto alloc = [&](size_t bytes) -> void* {
        void* p = ws + off;
        off += (bytes + 255) & ~(size_t)255;
        return p;
    };
    float* h0     = (float*)alloc((size_t)N * 64 * 4);   // reused as h2lin
    float* h1     = (float*)alloc((size_t)N * 256 * 4);
    float* as1    = (float*)alloc((size_t)N * 4 * 4);
    float* ad1    = (float*)alloc((size_t)N * 4 * 4);
    float* as2    = (float*)alloc((size_t)N * 4);
    float* ad2    = (float*)alloc((size_t)N * 4);
    int*   deg    = (int*)alloc((size_t)N * 4);
    int*   rowptr = (int*)alloc((size_t)(N + 1) * 4);
    int*   cursor = (int*)alloc((size_t)N * 4);
    int*   parts  = (int*)alloc(1024 * 4);
    int*   csrc   = (int*)alloc((size_t)total * 4);
    int*   cdst   = (int*)alloc((size_t)total * 4);
    float* wexp1  = (float*)alloc((size_t)total * 4 * 4);
    float* wt0    = (float*)alloc(64 * KP_PROJ * 4);
    float* wt2    = (float*)alloc(64 * 256 * 4);
    float* va     = (float*)alloc(512 * 4);
    float* h2lin  = h0;

    // weight transposes + va vectors
    k_trans<<<(64 * KP_PROJ + 64 * 256 + 512 + 255) / 256, 256, 0, stream>>>(
        projW, W2, W1, as1w, ad1w, wt0, wt2, va);

    // CSR build
    hipMemsetAsync(deg, 0, (size_t)N * 4, stream);
    hipMemsetAsync(cursor, 0, (size_t)N * 4, stream);
    k_deg<<<1024, 256, 0, stream>>>(ei, E, N, deg);
    int nblk = (N + 1023) / 1024;
    k_scan_part<<<nblk, 1024, 0, stream>>>(deg, rowptr, parts, N);
    k_scan_small<<<1, 64, 0, stream>>>(parts, nblk);
    k_scan_add<<<nblk, 1024, 0, stream>>>(rowptr, parts, N, total);
    k_scatter<<<1024, 256, 0, stream>>>(ei, E, N, rowptr, cursor, csrc, cdst);

    // MLP in
    k_proj<<<(N + 31) / 32, 256, 0, stream>>>(x, wt0, projB, h0, N);

    // GAT layer 1 (h0-domain aggregation)
    k_attv1<<<(N + 3) / 4, 256, 0, stream>>>(h0, va, as1, ad1, N);
    k_edgew1<<<2048, 256, 0, stream>>>(csrc, cdst, as1, ad1, wexp1, total);
    k_gat1f<<<(N + 3) / 4, 256, 0, stream>>>(h0, wexp1, rowptr, csrc, W1, b1, h1, N);

    // GAT layer 2 + classifier (edge weights fused into k_gat2)
    k_lin2<<<(N + 31) / 32, 256, 0, stream>>>(h1, wt2, as2w, ad2w, h2lin, as2, ad2, N);
    k_gat2<<<(N + 3) / 4, 256, 0, stream>>>(h2lin, as2, ad2, rowptr, csrc, b2,
                                            clsW, clsB, out, N);
}